// Round 15
// baseline (2516.668 us; speedup 1.0000x reference)
//
#include <hip/hip_runtime.h>
#include <hip/hip_bf16.h>
#include <math.h>

#define S_LEN 1024
#define DIM   2048
#define NHQ   16
#define NHKV  4
#define HDIM  128
#define PDIM  8192
#define VOCAB 32000
#define NLAYER 4
#define NROWS (2 * S_LEN)   // B*S = 2048

typedef __attribute__((ext_vector_type(4))) float f32x4;
typedef __attribute__((ext_vector_type(8))) short bf16x8;

__device__ __forceinline__ void gload_lds16(const void* g, void* l) {
  __builtin_amdgcn_global_load_lds(
      (const __attribute__((address_space(1))) unsigned int*)g,
      (__attribute__((address_space(3))) unsigned int*)l, 16, 0, 0);
}

#define FENCE() asm volatile("" ::: "memory")

// ---------------- embedding gather (f32) ----------------
__global__ __launch_bounds__(256) void k_embed(const int* __restrict__ tokens,
    const float* __restrict__ emb, float* __restrict__ x) {
  int row = blockIdx.x;
  int tok = tokens[row];
  const f32x4* src = (const f32x4*)(emb + (size_t)tok * DIM);
  f32x4* dst = (f32x4*)(x + (size_t)row * DIM);
  for (int i = threadIdx.x; i < DIM / 4; i += 256) dst[i] = src[i];
}

// ---------------- rmsnorm f32 -> bf16 ----------------
__global__ __launch_bounds__(256) void k_rmsnorm(const float* __restrict__ x,
    const float* __restrict__ w, __hip_bfloat16* __restrict__ out) {
  int row = blockIdx.x;
  const float* xr = x + (size_t)row * DIM;
  float ss = 0.f;
  for (int i = threadIdx.x; i < DIM; i += 256) { float v = xr[i]; ss += v * v; }
  for (int off = 32; off; off >>= 1) ss += __shfl_xor(ss, off);
  __shared__ float wsum[4];
  if ((threadIdx.x & 63) == 0) wsum[threadIdx.x >> 6] = ss;
  __syncthreads();
  float tot = wsum[0] + wsum[1] + wsum[2] + wsum[3];
  float r = rsqrtf(tot / (float)DIM + 1e-5f);
  __hip_bfloat16* orow = out + (size_t)row * DIM;
  for (int i = threadIdx.x; i < DIM; i += 256)
    orow[i] = __float2bfloat16(w[i] * (xr[i] * r));
}

// ---------------- weight transpose+convert: W[K][N] f32 -> WT[N][K] bf16 ----------------
__global__ __launch_bounds__(256) void k_wt(const float* __restrict__ W,
    __hip_bfloat16* __restrict__ WT, int K, int N) {
  __shared__ __hip_bfloat16 t[64][72];   // [n][k], +8 pad
  int k0 = blockIdx.y * 64, n0 = blockIdx.x * 64;
  int r = threadIdx.x >> 4;          // 0..15
  int c4 = (threadIdx.x & 15) * 4;   // 0..60
#pragma unroll
  for (int i = 0; i < 4; ++i) {
    int k = r + i * 16;
    f32x4 v = *(const f32x4*)(W + (size_t)(k0 + k) * N + n0 + c4);
#pragma unroll
    for (int j = 0; j < 4; ++j) t[c4 + j][k] = __float2bfloat16(v[j]);
  }
  __syncthreads();
  int n = threadIdx.x >> 2, kc = (threadIdx.x & 3) * 16;
  bf16x8* dst = (bf16x8*)(WT + (size_t)(n0 + n) * K + k0 + kc);
  dst[0] = *(const bf16x8*)&t[n][kc];
  dst[1] = *(const bf16x8*)&t[n][kc + 8];
}

// ---- gate_up transpose with 16-col gate/up interleave (r11 version):
__global__ __launch_bounds__(256) void k_wt_gu(const float* __restrict__ W,
    __hip_bfloat16* __restrict__ WT, int K, int N) {
  __shared__ __hip_bfloat16 t[64][72];
  int k0 = blockIdx.y * 64, n0 = blockIdx.x * 64;
  int r = threadIdx.x >> 4;
  int c4 = (threadIdx.x & 15) * 4;
  int nblk = (n0 + c4) >> 4;
  int jj   = (n0 + c4) & 15;
  int srcc = ((nblk & 1) ? PDIM : 0) + ((nblk >> 1) << 4) + jj;
#pragma unroll
  for (int i = 0; i < 4; ++i) {
    int k = r + i * 16;
    f32x4 v = *(const f32x4*)(W + (size_t)(k0 + k) * N + srcc);
#pragma unroll
    for (int j = 0; j < 4; ++j) t[c4 + j][k] = __float2bfloat16(v[j]);
  }
  __syncthreads();
  int n = threadIdx.x >> 2, kc = (threadIdx.x & 3) * 16;
  bf16x8* dst = (bf16x8*)(WT + (size_t)(n0 + n) * K + k0 + kc);
  dst[0] = *(const bf16x8*)&t[n][kc];
  dst[1] = *(const bf16x8*)&t[n][kc + 8];
}

// ---------------- big GEMM: 256x256, per-half-K phases, 4-slot LDS ring (r11) ----------------
// KSPLIT>1: blockIdx.y selects K-slice of length K/KSPLIT.
// EPI: 0 = store f32, 1 = add into f32, 2 = store bf16,
//      3 = fused swiglu (k_wt_gu layout; h width = N/2), 4 = atomicAdd f32.
template<int EPI, int KSPLIT = 1>
__global__ __launch_bounds__(512) void k_gemm256(
    const __hip_bfloat16* __restrict__ A, const __hip_bfloat16* __restrict__ BT,
    void* __restrict__ Cv, int M, int N, int K) {
  __shared__ __hip_bfloat16 AsH[4][128][64];   // 64 KiB (4 ring slots)
  __shared__ __hip_bfloat16 BsH[4][128][64];   // 64 KiB
  const int Keff = K / KSPLIT;
  const int kbase = (KSPLIT > 1) ? (int)blockIdx.y * Keff : 0;
  const int NH = Keff >> 5;                    // number of K=32 halves
  int tid = threadIdx.x;
  int bid = blockIdx.x;
  int mt = bid & 7, nt = bid >> 3;             // XCD x owns m-strip x, sweeps n
  int bm = mt << 8, bn = nt << 8;
  int wave = tid >> 6, lane = tid & 63;
  int wm = wave >> 2, wn = wave & 3;           // 2x4 wave grid
  int g = lane >> 4, c = lane & 15;
  f32x4 acc[8][4] = {};

  int pre  = (lane & 7) ^ (lane >> 3);
  int rOff = (lane >> 3) * 2 + (pre >> 2);
  int cOff = (pre & 3) * 8;

  auto stageA = [&](int S, int h) {
#pragma unroll
    for (int rd = 0; rd < 2; ++rd) {
      int seg = rd * 8 + wave;
      gload_lds16(A + (size_t)(bm + seg * 16 + rOff) * K + kbase + h * 32 + cOff,
                  &AsH[S][seg * 8 + (lane >> 3)][(lane & 7) * 8]);
    }
  };
  auto stageB = [&](int S, int h) {
#pragma unroll
    for (int rd = 0; rd < 2; ++rd) {
      int seg = rd * 8 + wave;
      gload_lds16(BT + (size_t)(bn + seg * 16 + rOff) * K + kbase + h * 32 + cOff,
                  &BsH[S][seg * 8 + (lane >> 3)][(lane & 7) * 8]);
    }
  };

  // prologue: A0,B0,A1,B1,B2 (10 insts); vmcnt(6) completes half 0
  stageA(0, 0); stageB(0, 0);
  stageA(1, 1); stageB(1, 1);
  stageB(2, 2);
  asm volatile("s_waitcnt vmcnt(6)" ::: "memory");
  __builtin_amdgcn_s_barrier();
  FENCE();

  int lineA = wm * 64 + (c >> 1);
  int lineB = wn * 32 + (c >> 1);
  int slotE = ((((c & 1) << 2) | g) ^ (c >> 1)) * 8;

  for (int H = 0; H < NH; ++H) {
    int S = H & 3;
    bf16x8 af[8], bv[4];
#pragma unroll
    for (int mi = 0; mi < 8; ++mi)
      af[mi] = *(const bf16x8*)&AsH[S][lineA + mi * 8][slotE];
#pragma unroll
    for (int ni = 0; ni < 4; ++ni)
      bv[ni] = *(const bf16x8*)&BsH[S][lineB + ni * 8][slotE];
    FENCE();
    if (H + 2 < NH) stageA((H + 2) & 3, H + 2);
    if (H + 3 < NH) stageB((H + 3) & 3, H + 3);
    if (H + 4 <= NH)      { asm volatile("s_waitcnt vmcnt(6)" ::: "memory"); }
    else if (H + 3 == NH) { asm volatile("s_waitcnt vmcnt(4)" ::: "memory"); }
    else if (H + 2 == NH) { asm volatile("s_waitcnt vmcnt(0)" ::: "memory"); }
    __builtin_amdgcn_s_barrier();
    asm volatile("s_waitcnt lgkmcnt(0)" ::: "memory");
    __builtin_amdgcn_sched_barrier(0);
    __builtin_amdgcn_s_setprio(1);
#pragma unroll
    for (int mi = 0; mi < 8; ++mi)
#pragma unroll
      for (int ni = 0; ni < 4; ++ni)
        acc[mi][ni] = __builtin_amdgcn_mfma_f32_16x16x32_bf16(af[mi], bv[ni], acc[mi][ni], 0, 0, 0);
    __builtin_amdgcn_s_setprio(0);
    FENCE();
    __builtin_amdgcn_s_barrier();
    FENCE();
  }

  float* Cf = (float*)Cv;
  __hip_bfloat16* Cb = (__hip_bfloat16*)Cv;
  int row0 = bm + wm * 128, col0 = bn + wn * 64;
  if (EPI == 3) {
#pragma unroll
    for (int mi = 0; mi < 8; ++mi)
#pragma unroll
      for (int ni = 0; ni < 4; ni += 2)
#pragma unroll
        for (int r = 0; r < 4; ++r) {
          int row = row0 + mi * 16 + g * 4 + r;
          int hcol = ((col0 + ni * 16) >> 1) + c;
          float gate = acc[mi][ni][r], up = acc[mi][ni + 1][r];
          float sv = gate / (1.f + __expf(-gate)) * up;
          Cb[(size_t)row * PDIM + hcol] = __float2bfloat16(sv);
        }
  } else {
#pragma unroll
    for (int mi = 0; mi < 8; ++mi)
#pragma unroll
      for (int ni = 0; ni < 4; ++ni)
#pragma unroll
        for (int r = 0; r < 4; ++r) {
          int row = row0 + mi * 16 + g * 4 + r;
          int col = col0 + ni * 16 + c;
          size_t idx = (size_t)row * N + col;
          if (EPI == 0) Cf[idx] = acc[mi][ni][r];
          else if (EPI == 1) Cf[idx] += acc[mi][ni][r];
          else if (EPI == 2) Cb[idx] = __float2bfloat16(acc[mi][ni][r]);
          else atomicAdd(&Cf[idx], acc[mi][ni][r]);
        }
  }
}

// ---------------- 128x128 GEMM, BK=64, counted-vmcnt 2-deep, swizzled LDS ----------------
template<int EPI, int KSPLIT = 1>
__global__ __launch_bounds__(256) void k_gemm_bt(
    const __hip_bfloat16* __restrict__ A, const __hip_bfloat16* __restrict__ BT,
    void* __restrict__ Cv, int M, int N, int K) {
  __shared__ __hip_bfloat16 As[2][128][64];   // 32 KiB
  __shared__ __hip_bfloat16 Bs[2][128][64];   // 32 KiB
  int nm = M >> 7;
  int bid = blockIdx.x;
  int mt, nt;
  if (nm == 16) {
    int xcd = bid & 7;
    int seq = bid >> 3;
    mt = (xcd << 1) | (seq & 1);
    nt = seq >> 1;
  } else {
    mt = bid % nm;
    nt = bid / nm;
  }
  int bm = mt << 7, bn = nt << 7;
  const int Keff = K / KSPLIT;
  const int kbase = (KSPLIT > 1) ? (int)blockIdx.y * Keff : 0;
  int tid  = threadIdx.x;
  int wave = tid >> 6, lane = tid & 63;
  int wr = (wave >> 1) * 64, wc = (wave & 1) * 64;
  int g = lane >> 4, c = lane & 15;
  f32x4 acc[4][4] = {};

  auto stage = [&](int buf, int k0) {   // 8 vmem insts/wave
#pragma unroll
    for (int i = 0; i < 4; ++i) {
      int ci = i * 256 + tid;            // 0..1023
      int row = ci >> 3, pc = ci & 7;
      int jl = pc ^ (row & 7);
      gload_lds16(A + (size_t)(bm + row) * K + kbase + k0 + jl * 8, &As[buf][row][pc * 8]);
      gload_lds16(BT + (size_t)(bn + row) * K + kbase + k0 + jl * 8, &Bs[buf][row][pc * 8]);
    }
  };

  int ntiles = Keff >> 6;
  stage(0, 0);
  if (ntiles > 1) stage(1, 64);

  for (int t = 0; t < ntiles; ++t) {
    int cur = t & 1;
    if (t + 1 < ntiles) asm volatile("s_waitcnt vmcnt(8)" ::: "memory");
    else                asm volatile("s_waitcnt vmcnt(0)" ::: "memory");
    __builtin_amdgcn_s_barrier();
    FENCE();
    __builtin_amdgcn_sched_barrier(0);
#pragma unroll
    for (int kk = 0; kk < 2; ++kk) {
      bf16x8 af[4], bv[4];
#pragma unroll
      for (int mi = 0; mi < 4; ++mi) {
        int row = wr + mi * 16 + c;
        int ch = (kk * 4 + g) ^ (row & 7);
        af[mi] = *(const bf16x8*)&As[cur][row][ch * 8];
      }
#pragma unroll
      for (int ni = 0; ni < 4; ++ni) {
        int row = wc + ni * 16 + c;
        int ch = (kk * 4 + g) ^ (row & 7);
        bv[ni] = *(const bf16x8*)&Bs[cur][row][ch * 8];
      }
      __builtin_amdgcn_s_setprio(1);
#pragma unroll
      for (int mi = 0; mi < 4; ++mi)
#pragma unroll
        for (int ni = 0; ni < 4; ++ni)
          acc[mi][ni] = __builtin_amdgcn_mfma_f32_16x16x32_bf16(af[mi], bv[ni], acc[mi][ni], 0, 0, 0);
      __builtin_amdgcn_s_setprio(0);
    }
    FENCE();
    __builtin_amdgcn_s_barrier();
    FENCE();
    if (t + 2 < ntiles) stage(cur, (t + 2) << 6);
  }

  float* Cf = (float*)Cv;
  __hip_bfloat16* Cb = (__hip_bfloat16*)Cv;
#pragma unroll
  for (int mi = 0; mi < 4; ++mi)
#pragma unroll
    for (int ni = 0; ni < 4; ++ni)
#pragma unroll
      for (int r = 0; r < 4; ++r) {
        int row = bm + wr + mi * 16 + g * 4 + r;
        int col = bn + wc + ni * 16 + c;
        size_t idx = (size_t)row * N + col;
        if (EPI == 0) Cf[idx] = acc[mi][ni][r];
        else if (EPI == 1) Cf[idx] += acc[mi][ni][r];
        else if (EPI == 2) Cb[idx] = __float2bfloat16(acc[mi][ni][r]);
        else atomicAdd(&Cf[idx], acc[mi][ni][r]);
      }
}

// ---------------- fallback GEMM: B from f32 weights ----------------
template<int EPI>
__global__ __launch_bounds__(256) void k_gemm(
    const __hip_bfloat16* __restrict__ A, const float* __restrict__ Bw,
    void* __restrict__ Cv, int M, int N, int K) {
  __shared__ __hip_bfloat16 As[128][32];
  __shared__ __hip_bfloat16 Bs[128][40];
  int tid  = threadIdx.x;
  int bm = blockIdx.y * 128, bn = blockIdx.x * 128;
  int wave = tid >> 6, lane = tid & 63;
  int wr = (wave >> 1) * 64, wc = (wave & 1) * 64;
  int lrow = lane & 15, lk = (lane >> 4) * 8;
  f32x4 acc[4][4] = {};
  for (int k0 = 0; k0 < K; k0 += 32) {
#pragma unroll
    for (int i = 0; i < 2; ++i) {
      int L = i * 256 + tid;
      int row = L >> 2, koff = (L & 3) * 8;
      gload_lds16(A + (size_t)(bm + row) * K + k0 + koff, &As[row][koff]);
    }
#pragma unroll
    for (int i = 0; i < 4; ++i) {
      int L = i * 256 + tid;
      int kk = L >> 5;
      int c4 = (L & 31) * 4;
      f32x4 v = *(const f32x4*)(Bw + (size_t)(k0 + kk) * N + bn + c4);
#pragma unroll
      for (int j = 0; j < 4; ++j) Bs[c4 + j][kk] = __float2bfloat16(v[j]);
    }
    __syncthreads();
    bf16x8 af[4], bfr[4];
#pragma unroll
    for (int mi = 0; mi < 4; ++mi)
      af[mi] = *(const bf16x8*)(&As[wr + mi * 16 + lrow][lk]);
#pragma unroll
    for (int ni = 0; ni < 4; ++ni)
      bfr[ni] = *(const bf16x8*)(&Bs[wc + ni * 16 + lrow][lk]);
#pragma unroll
    for (int mi = 0; mi < 4; ++mi)
#pragma unroll
      for (int ni = 0; ni < 4; ++ni)
        acc[mi][ni] = __builtin_amdgcn_mfma_f32_16x16x32_bf16(af[mi], bfr[ni], acc[mi][ni], 0, 0, 0);
    __syncthreads();
  }
  float* Cf = (float*)Cv;
  __hip_bfloat16* Cb = (__hip_bfloat16*)Cv;
#pragma unroll
  for (int mi = 0; mi < 4; ++mi)
#pragma unroll
    for (int ni = 0; ni < 4; ++ni)
#pragma unroll
      for (int r = 0; r < 4; ++r) {
        int row = bm + wr + mi * 16 + ((lane >> 4) * 4 + r);
        int col = bn + wc + ni * 16 + (lane & 15);
        size_t idx = (size_t)row * N + col;
        if (EPI == 0) Cf[idx] = acc[mi][ni][r];
        else if (EPI == 1) Cf[idx] += acc[mi][ni][r];
        else Cb[idx] = __float2bfloat16(acc[mi][ni][r]);
      }
}

// ---------------- RoPE + QKV split/reorder (bf16 input; Q pre-scaled, V transposed) ----------------
__global__ __launch_bounds__(256) void k_rope(const __hip_bfloat16* __restrict__ qkv,
    __hip_bfloat16* __restrict__ qr, __hip_bfloat16* __restrict__ kr,
    __hip_bfloat16* __restrict__ vt) {
  int rowid = blockIdx.x;
  int b = rowid >> 10, s = rowid & (S_LEN - 1);
  const __hip_bfloat16* src = qkv + (size_t)rowid * 3072;
  const float kInvLog = 0.20503692777f;  // ln(500000)/64
  const float scale = 0.08838834764831845f;  // 1/sqrt(128)
  __shared__ float cs[64], sn[64];
  if (threadIdx.x < 64) {
    float inv = expf(-(float)threadIdx.x * kInvLog);
    float a = (float)s * inv;
    sincosf(a, &sn[threadIdx.x], &cs[threadIdx.x]);
  }
  __syncthreads();
  for (int it = threadIdx.x; it < NHQ * 64; it += 256) {
    int h = it >> 6, i = it & 63;
    float re = __bfloat162float(src[h * HDIM + i]);
    float im = __bfloat162float(src[h * HDIM + 64 + i]);
    size_t dst = ((size_t)(b * NHQ + h) * S_LEN + s) * HDIM;
    qr[dst + 2 * i]     = __float2bfloat16((re * cs[i] - im * sn[i]) * scale);
    qr[dst + 2 * i + 1] = __float2bfloat16((re * sn[i] + im * cs[i]) * scale);
  }
  for (int it = threadIdx.x; it < NHKV * 64; it += 256) {
    int h = it >> 6, i = it & 63;
    float re = __bfloat162float(src[DIM + h * HDIM + i]);
    float im = __bfloat162float(src[DIM + h * HDIM + 64 + i]);
    size_t dst = ((size_t)(b * NHKV + h) * S_LEN + s) * HDIM;
    kr[dst + 2 * i]     = __float2bfloat16(re * cs[i] - im * sn[i]);
    kr[dst + 2 * i + 1] = __float2bfloat16(re * sn[i] + im * cs[i]);
  }
  // V transposed: vt[b][hk][hd][s]
  for (int it = threadIdx.x; it < NHKV * HDIM; it += 256) {
    int h = it >> 7, d = it & 127;
    vt[(((size_t)b * NHKV + h) * HDIM + d) * S_LEN + s] = src[DIM + NHKV * HDIM + it];
  }
}

// ---------------- MFMA flash attention: 32 q-rows/wave, shared K/V tiles ----------------
__global__ __launch_bounds__(256) void k_attn_mfma(
    const __hip_bfloat16* __restrict__ Q,   // [B][HQ][S][HD]
    const __hip_bfloat16* __restrict__ Kc,  // [B][HKV][S][HD]
    const __hip_bfloat16* __restrict__ VT,  // [B][HKV][HD][S]
    __hip_bfloat16* __restrict__ O) {       // [B*S][2048], col = h*128+d
  __shared__ __hip_bfloat16 plds[4][32][40];
  int wave = threadIdx.x >> 6, lane = threadIdx.x & 63;
  int gw = blockIdx.x * 4 + wave;     // 0 .. B*HQ*(S/32)-1
  int qt = gw & 31;
  int bh = gw >> 5;                   // b*HQ + h
  int b = bh >> 4, h = bh & 15;
  int hk = h >> 2;
  int q0 = qt * 32;
  int g = lane >> 4, c = lane & 15;
  const __hip_bfloat16* Qb = Q + ((size_t)bh * S_LEN + q0) * HDIM;
  const __hip_bfloat16* Kb = Kc + (size_t)(b * NHKV + hk) * S_LEN * HDIM;
  const __hip_bfloat16* Vb = VT + (size_t)(b * NHKV + hk) * S_LEN * HDIM;

  bf16x8 qf[2][4];
#pragma unroll
  for (int f = 0; f < 2; ++f)
#pragma unroll
    for (int cn = 0; cn < 4; ++cn)
      qf[f][cn] = *(const bf16x8*)(Qb + (size_t)(f * 16 + c) * HDIM + cn * 32 + g * 8);

  f32x4 po[2][8] = {};
  float m[2][4], l[2][4];
#pragma unroll
  for (int f = 0; f < 2; ++f)
#pragma unroll
    for (int r = 0; r < 4; ++r) { m[f][r] = -1e30f; l[f][r] = 0.f; }

  int kvend = q0 + 32;
  for (int kv0 = 0; kv0 < kvend; kv0 += 32) {
    f32x4 s0[2] = {}, s1[2] = {};
#pragma unroll
    for (int cn = 0; cn < 4; ++cn) {
      bf16x8 k0f = *(const bf16x8*)(Kb + (size_t)(kv0 + c) * HDIM + cn * 32 + g * 8);
      bf16x8 k1f = *(const bf16x8*)(Kb + (size_t)(kv0 + 16 + c) * HDIM + cn * 32 + g * 8);
#pragma unroll
      for (int f = 0; f < 2; ++f) {
        s0[f] = __builtin_amdgcn_mfma_f32_16x16x32_bf16(qf[f][cn], k0f, s0[f], 0, 0, 0);
        s1[f] = __builtin_amdgcn_mfma_f32_16x16x32_bf16(qf[f][cn], k1f, s1[f], 0, 0, 0);
      }
    }
    if (kv0 + 31 > q0) {               // aligned diagonal tile only (kv0 == q0)
#pragma unroll
      for (int f = 0; f < 2; ++f)
#pragma unroll
        for (int r = 0; r < 4; ++r) {
          int qrow = q0 + f * 16 + g * 4 + r;
          if (kv0 + c > qrow)      s0[f][r] = -1e30f;
          if (kv0 + 16 + c > qrow) s1[f][r] = -1e30f;
        }
    }
#pragma unroll
    for (int f = 0; f < 2; ++f) {
      float rm[4];
#pragma unroll
      for (int r = 0; r < 4; ++r) rm[r] = fmaxf(s0[f][r], s1[f][r]);
#pragma unroll
      for (int off = 1; off < 16; off <<= 1)
#pragma unroll
        for (int r = 0; r < 4; ++r) rm[r] = fmaxf(rm[r], __shfl_xor(rm[r], off));
      float p0[4], p1[4], rs[4];
#pragma unroll
      for (int r = 0; r < 4; ++r) {
        float mn = fmaxf(m[f][r], rm[r]);
        float corr = __expf(m[f][r] - mn);
        m[f][r] = mn;
        p0[r] = __expf(s0[f][r] - mn);
        p1[r] = __expf(s1[f][r] - mn);
        rs[r] = p0[r] + p1[r];
        l[f][r] *= corr;
#pragma unroll
        for (int t = 0; t < 8; ++t) po[f][t][r] *= corr;
      }
#pragma unroll
      for (int off = 1; off < 16; off <<= 1)
#pragma unroll
        for (int r = 0; r < 4; ++r) rs[r] += __shfl_xor(rs[r], off);
#pragma unroll
      for (int r = 0; r < 4; ++r) l[f][r] += rs[r];
#pragma unroll
      for (int r = 0; r < 4; ++r) {
        plds[wave][f * 16 + g * 4 + r][c]      = __float2bfloat16(p0[r]);
        plds[wave][f * 16 + g * 4 + r][16 + c] = __float2bfloat16(p1[r]);
      }
    }
    bf16x8 pf[2];
#pragma unroll
    for (int f = 0; f < 2; ++f)
      pf[f] = *(const bf16x8*)&plds[wave][f * 16 + c][g * 8];
#pragma unroll
    for (int t = 0; t < 8; ++t) {
      bf16x8 vf = *(const bf16x8*)(Vb + (size_t)(t * 16 + c) * S_LEN + kv0 + g * 8);
#pragma unroll
      for (int f = 0; f < 2; ++f)
        po[f][t] = __builtin_amdgcn_mfma_f32_16x16x32_bf16(pf[f], vf, po[f][t], 0, 0, 0);
    }
  }
#pragma unroll
  for (int f = 0; f < 2; ++f) {
    float inv[4];
#pragma unroll
    for (int r = 0; r < 4; ++r) inv[r] = 1.f / l[f][r];
    __hip_bfloat16* ob = O + ((size_t)(b * S_LEN) + q0 + f * 16) * DIM + h * HDIM;
#pragma unroll
    for (int t = 0; t < 8; ++t)
#pragma unroll
      for (int r = 0; r < 4; ++r)
        ob[(size_t)(g * 4 + r) * DIM + t * 16 + c] = __float2bfloat16(po[f][t][r] * inv[r]);
  }
}

extern "C" void kernel_launch(void* const* d_in, const int* in_sizes, int n_in,
                              void* d_out, int out_size, void* d_ws, size_t ws_size,
                              hipStream_t stream) {
  const int*   tokens    = (const int*)d_in[0];
  const float* emb       = (const float*)d_in[1];
  const float* w_qkv     = (const float*)d_in[2];
  const float* w_o       = (const float*)d_in[3];
  const float* w_gate_up = (const float*)d_in[4];
  const float* w_down    = (const float*)d_in[5];
  const float* ln_attn   = (const float*)d_in[6];
  const float* ln_ffn    = (const float*)d_in[7];
  const float* ln_f      = (const float*)d_in[8];
  const float* w_lm      = (const float*)d_in[9];
  float* out = (float*)d_out;

  char* ws = (char*)d_ws;
  float* x = (float*)ws;                    ws += (size_t)NROWS * DIM * 4;
  __hip_bfloat16* xn = (__hip_bfloat16*)ws; ws += (size_t)NROWS * DIM * 2;
  __hip_bfloat16* qkvb = (__hip_bfloat16*)ws; ws += (size_t)NROWS * 3072 * 2;
  __hip_bfloat16* qr = (__hip_bfloat16*)ws; ws += (size_t)2 * NHQ * S_LEN * HDIM * 2;
  __hip_bfloat16* kr = (__hip_bfloat16*)ws; ws += (size_t)2 * NHKV * S_LEN * HDIM * 2;
  __hip_bfloat16* vt = (__hip_bfloat16*)ws; ws += (size_t)2 * NHKV * S_LEN * HDIM * 2;
  __hip_bfloat16* ao = (__hip_bfloat16*)ws; ws += (size_t)NROWS * DIM * 2;
  __hip_bfloat16* hb = (__hip_bfloat16*)ws; ws += (size_t)NROWS * PDIM * 2;
  __hip_bfloat16* wbuf = (__hip_bfloat16*)ws;           // JIT bf16 W^T buffer
  size_t need = (size_t)(ws - (char*)d_ws) + (size_t)VOCAB * DIM * 2;
  bool bf16w = ws_size >= need;

  k_embed<<<NROWS, 256, 0, stream>>>(tokens, emb, x);

  for (int l = 0; l < NLAYER; ++l) {
    k_rmsnorm<<<NROWS, 256, 0, stream>>>(x, ln_attn + (size_t)l * DIM, xn);
    if (bf16w) {
      k_wt<<<dim3(3072 / 64, DIM / 64), 256, 0, stream>>>(
          w_qkv + (size_t)l * DIM * 3072, wbuf, DIM, 3072);
      k_gemm_bt<2><<<(NROWS / 128) * (3072 / 128), 256, 0, stream>>>(
          xn, wbuf, qkvb, NROWS, 3072, DIM);
    } else {
      k_gemm<2><<<dim3(3072 / 128, NROWS / 128), 256, 0, stream>>>(
          xn, w_qkv + (size_t)l * DIM * 3072, qkvb, NROWS, 3072, DIM);
    }
    k_rope<<<NROWS, 256, 0, stream>>>(qkvb, qr, kr, vt);
    k_attn_mfma<<<(2 * NHQ * (S_LEN / 32)) / 4, 256, 0, stream>>>(qr, kr, vt, ao);
    if (bf16w) {
      k_wt<<<dim3(DIM / 64, DIM / 64), 256, 0, stream>>>(
          w_o + (size_t)l * DIM * DIM, wbuf, DIM, DIM);
      // o-proj: 256^2 tile, split-K=4 -> 64 x 4 = 256 blocks, atomicAdd into x
      k_gemm256<4, 4><<<dim3(8 * (DIM / 256), 4), 512, 0, stream>>>(
          ao, wbuf, x, NROWS, DIM, DIM);
    } else {
      k_gemm<1><<<dim3(DIM / 128, NROWS / 128), 256, 0, stream>>>(
          ao, w_o + (size_t)l * DIM * DIM, x, NROWS, DIM, DIM);
    }
    k_rmsnorm<<<NROWS, 256, 0, stream>>>(x, ln_ffn + (size_t)l * DIM, xn);
    if (bf16w) {
      k_wt_gu<<<dim3(2 * PDIM / 64, DIM / 64), 256, 0, stream>>>(
          w_gate_up + (size_t)l * DIM * 2 * PDIM, wbuf, DIM, 2 * PDIM);
      k_gemm256<3><<<8 * (2 * PDIM / 256), 512, 0, stream>>>(
          xn, wbuf, hb, NROWS, 2 * PDIM, DIM);
    } else {
      k_gemm<2><<<dim3(2 * PDIM / 128, NROWS / 128), 256, 0, stream>>>(
          xn, w_gate_up + (size_t)l * DIM * 2 * PDIM, (void*)hb, NROWS, 2 * PDIM, DIM);
    }
    if (bf16w) {
      k_wt<<<dim3(DIM / 64, PDIM / 64), 256, 0, stream>>>(
          w_down + (size_t)l * PDIM * DIM, wbuf, PDIM, DIM);
      // down-proj: 256^2 tile, split-K=4 -> 64 x 4 = 256 blocks, atomicAdd into x
      k_gemm256<4, 4><<<dim3(8 * (DIM / 256), 4), 512, 0, stream>>>(
          hb, wbuf, x, NROWS, DIM, PDIM);
    } else {
      k_gemm<1><<<dim3(DIM / 128, NROWS / 128), 256, 0, stream>>>(
          hb, w_down + (size_t)l * PDIM * DIM, x, NROWS, DIM, PDIM);
    }
  }

  k_rmsnorm<<<NROWS, 256, 0, stream>>>(x, ln_f, xn);
  if (bf16w) {
    k_wt<<<dim3(VOCAB / 64, DIM / 64), 256, 0, stream>>>(w_lm, wbuf, DIM, VOCAB);
    k_gemm256<0><<<8 * (VOCAB / 256), 512, 0, stream>>>(
        xn, wbuf, out, NROWS, VOCAB, DIM);
  } else {
    k_gemm<0><<<dim3(VOCAB / 128, NROWS / 128), 256, 0, stream>>>(
        xn, w_lm, out, NROWS, VOCAB, DIM);
  }
}

// Round 16
// 2318.974 us; speedup vs baseline: 1.0853x; 1.0853x over previous
//
#include <hip/hip_runtime.h>
#include <hip/hip_bf16.h>
#include <math.h>

#define S_LEN 1024
#define DIM   2048
#define NHQ   16
#define NHKV  4
#define HDIM  128
#define PDIM  8192
#define VOCAB 32000
#define NLAYER 4
#define NROWS (2 * S_LEN)   // B*S = 2048

typedef __attribute__((ext_vector_type(4))) float f32x4;
typedef __attribute__((ext_vector_type(8))) short bf16x8;

__device__ __forceinline__ void gload_lds16(const void* g, void* l) {
  __builtin_amdgcn_global_load_lds(
      (const __attribute__((address_space(1))) unsigned int*)g,
      (__attribute__((address_space(3))) unsigned int*)l, 16, 0, 0);
}

#define FENCE() asm volatile("" ::: "memory")

// ---------------- embedding gather (f32) ----------------
__global__ __launch_bounds__(256) void k_embed(const int* __restrict__ tokens,
    const float* __restrict__ emb, float* __restrict__ x) {
  int row = blockIdx.x;
  int tok = tokens[row];
  const f32x4* src = (const f32x4*)(emb + (size_t)tok * DIM);
  f32x4* dst = (f32x4*)(x + (size_t)row * DIM);
  for (int i = threadIdx.x; i < DIM / 4; i += 256) dst[i] = src[i];
}

// ---------------- rmsnorm f32 -> bf16 (f32x4 vectorized, 512 threads) ----------------
__global__ __launch_bounds__(512) void k_rmsnorm(const float* __restrict__ x,
    const float* __restrict__ w, __hip_bfloat16* __restrict__ out) {
  int row = blockIdx.x;
  const f32x4* xr = (const f32x4*)(x + (size_t)row * DIM);
  int i = threadIdx.x;                 // 512 threads x 4 elems = 2048
  f32x4 v = xr[i];
  float ss = v[0] * v[0] + v[1] * v[1] + v[2] * v[2] + v[3] * v[3];
  for (int off = 32; off; off >>= 1) ss += __shfl_xor(ss, off);
  __shared__ float wsum[8];
  if ((threadIdx.x & 63) == 0) wsum[threadIdx.x >> 6] = ss;
  __syncthreads();
  float tot = wsum[0] + wsum[1] + wsum[2] + wsum[3] +
              wsum[4] + wsum[5] + wsum[6] + wsum[7];
  float r = rsqrtf(tot / (float)DIM + 1e-5f);
  f32x4 wv = *(const f32x4*)(w + i * 4);
  __hip_bfloat16 ov[4];
#pragma unroll
  for (int j = 0; j < 4; ++j) ov[j] = __float2bfloat16(wv[j] * (v[j] * r));
  *(unsigned long long*)(out + (size_t)row * DIM + i * 4) = *(const unsigned long long*)ov;
}

// ---------------- weight transpose+convert: W[K][N] f32 -> WT[N][K] bf16 ----------------
__global__ __launch_bounds__(256) void k_wt(const float* __restrict__ W,
    __hip_bfloat16* __restrict__ WT, int K, int N) {
  __shared__ __hip_bfloat16 t[64][72];   // [n][k], +8 pad
  int k0 = blockIdx.y * 64, n0 = blockIdx.x * 64;
  int r = threadIdx.x >> 4;          // 0..15
  int c4 = (threadIdx.x & 15) * 4;   // 0..60
#pragma unroll
  for (int i = 0; i < 4; ++i) {
    int k = r + i * 16;
    f32x4 v = *(const f32x4*)(W + (size_t)(k0 + k) * N + n0 + c4);
#pragma unroll
    for (int j = 0; j < 4; ++j) t[c4 + j][k] = __float2bfloat16(v[j]);
  }
  __syncthreads();
  int n = threadIdx.x >> 2, kc = (threadIdx.x & 3) * 16;
  bf16x8* dst = (bf16x8*)(WT + (size_t)(n0 + n) * K + k0 + kc);
  dst[0] = *(const bf16x8*)&t[n][kc];
  dst[1] = *(const bf16x8*)&t[n][kc + 8];
}

// ---- gate_up transpose with 16-col gate/up interleave (r11 version):
__global__ __launch_bounds__(256) void k_wt_gu(const float* __restrict__ W,
    __hip_bfloat16* __restrict__ WT, int K, int N) {
  __shared__ __hip_bfloat16 t[64][72];
  int k0 = blockIdx.y * 64, n0 = blockIdx.x * 64;
  int r = threadIdx.x >> 4;
  int c4 = (threadIdx.x & 15) * 4;
  int nblk = (n0 + c4) >> 4;
  int jj   = (n0 + c4) & 15;
  int srcc = ((nblk & 1) ? PDIM : 0) + ((nblk >> 1) << 4) + jj;
#pragma unroll
  for (int i = 0; i < 4; ++i) {
    int k = r + i * 16;
    f32x4 v = *(const f32x4*)(W + (size_t)(k0 + k) * N + srcc);
#pragma unroll
    for (int j = 0; j < 4; ++j) t[c4 + j][k] = __float2bfloat16(v[j]);
  }
  __syncthreads();
  int n = threadIdx.x >> 2, kc = (threadIdx.x & 3) * 16;
  bf16x8* dst = (bf16x8*)(WT + (size_t)(n0 + n) * K + k0 + kc);
  dst[0] = *(const bf16x8*)&t[n][kc];
  dst[1] = *(const bf16x8*)&t[n][kc + 8];
}

// ---------------- big GEMM: 256x256, per-half-K phases, 4-slot LDS ring (r11) ----------------
// EPI: 0 = store f32, 1 = add into f32, 2 = store bf16,
//      3 = fused swiglu (k_wt_gu layout; h width = N/2).
template<int EPI>
__global__ __launch_bounds__(512) void k_gemm256(
    const __hip_bfloat16* __restrict__ A, const __hip_bfloat16* __restrict__ BT,
    void* __restrict__ Cv, int M, int N, int K) {
  __shared__ __hip_bfloat16 AsH[4][128][64];   // 64 KiB (4 ring slots)
  __shared__ __hip_bfloat16 BsH[4][128][64];   // 64 KiB
  const int NH = K >> 5;                       // number of K=32 halves
  int tid = threadIdx.x;
  int bid = blockIdx.x;
  int mt = bid & 7, nt = bid >> 3;             // XCD x owns m-strip x, sweeps n
  int bm = mt << 8, bn = nt << 8;
  int wave = tid >> 6, lane = tid & 63;
  int wm = wave >> 2, wn = wave & 3;           // 2x4 wave grid
  int g = lane >> 4, c = lane & 15;
  f32x4 acc[8][4] = {};

  int pre  = (lane & 7) ^ (lane >> 3);
  int rOff = (lane >> 3) * 2 + (pre >> 2);
  int cOff = (pre & 3) * 8;

  auto stageA = [&](int S, int h) {
#pragma unroll
    for (int rd = 0; rd < 2; ++rd) {
      int seg = rd * 8 + wave;
      gload_lds16(A + (size_t)(bm + seg * 16 + rOff) * K + h * 32 + cOff,
                  &AsH[S][seg * 8 + (lane >> 3)][(lane & 7) * 8]);
    }
  };
  auto stageB = [&](int S, int h) {
#pragma unroll
    for (int rd = 0; rd < 2; ++rd) {
      int seg = rd * 8 + wave;
      gload_lds16(BT + (size_t)(bn + seg * 16 + rOff) * K + h * 32 + cOff,
                  &BsH[S][seg * 8 + (lane >> 3)][(lane & 7) * 8]);
    }
  };

  // prologue: A0,B0,A1,B1,B2 (10 insts); vmcnt(6) completes half 0
  stageA(0, 0); stageB(0, 0);
  stageA(1, 1); stageB(1, 1);
  stageB(2, 2);
  asm volatile("s_waitcnt vmcnt(6)" ::: "memory");
  __builtin_amdgcn_s_barrier();
  FENCE();

  int lineA = wm * 64 + (c >> 1);
  int lineB = wn * 32 + (c >> 1);
  int slotE = ((((c & 1) << 2) | g) ^ (c >> 1)) * 8;

  for (int H = 0; H < NH; ++H) {
    int S = H & 3;
    bf16x8 af[8], bv[4];
#pragma unroll
    for (int mi = 0; mi < 8; ++mi)
      af[mi] = *(const bf16x8*)&AsH[S][lineA + mi * 8][slotE];
#pragma unroll
    for (int ni = 0; ni < 4; ++ni)
      bv[ni] = *(const bf16x8*)&BsH[S][lineB + ni * 8][slotE];
    FENCE();
    if (H + 2 < NH) stageA((H + 2) & 3, H + 2);
    if (H + 3 < NH) stageB((H + 3) & 3, H + 3);
    if (H + 4 <= NH)      { asm volatile("s_waitcnt vmcnt(6)" ::: "memory"); }
    else if (H + 3 == NH) { asm volatile("s_waitcnt vmcnt(4)" ::: "memory"); }
    else if (H + 2 == NH) { asm volatile("s_waitcnt vmcnt(0)" ::: "memory"); }
    __builtin_amdgcn_s_barrier();
    asm volatile("s_waitcnt lgkmcnt(0)" ::: "memory");
    __builtin_amdgcn_sched_barrier(0);
    __builtin_amdgcn_s_setprio(1);
#pragma unroll
    for (int mi = 0; mi < 8; ++mi)
#pragma unroll
      for (int ni = 0; ni < 4; ++ni)
        acc[mi][ni] = __builtin_amdgcn_mfma_f32_16x16x32_bf16(af[mi], bv[ni], acc[mi][ni], 0, 0, 0);
    __builtin_amdgcn_s_setprio(0);
    FENCE();
    __builtin_amdgcn_s_barrier();
    FENCE();
  }

  float* Cf = (float*)Cv;
  __hip_bfloat16* Cb = (__hip_bfloat16*)Cv;
  int row0 = bm + wm * 128, col0 = bn + wn * 64;
  if (EPI == 3) {
#pragma unroll
    for (int mi = 0; mi < 8; ++mi)
#pragma unroll
      for (int ni = 0; ni < 4; ni += 2)
#pragma unroll
        for (int r = 0; r < 4; ++r) {
          int row = row0 + mi * 16 + g * 4 + r;
          int hcol = ((col0 + ni * 16) >> 1) + c;
          float gate = acc[mi][ni][r], up = acc[mi][ni + 1][r];
          float sv = gate / (1.f + __expf(-gate)) * up;
          Cb[(size_t)row * PDIM + hcol] = __float2bfloat16(sv);
        }
  } else {
#pragma unroll
    for (int mi = 0; mi < 8; ++mi)
#pragma unroll
      for (int ni = 0; ni < 4; ++ni)
#pragma unroll
        for (int r = 0; r < 4; ++r) {
          int row = row0 + mi * 16 + g * 4 + r;
          int col = col0 + ni * 16 + c;
          size_t idx = (size_t)row * N + col;
          if (EPI == 0) Cf[idx] = acc[mi][ni][r];
          else if (EPI == 1) Cf[idx] += acc[mi][ni][r];
          else Cb[idx] = __float2bfloat16(acc[mi][ni][r]);
        }
  }
}

// ---------------- 128x128 GEMM, BK=64, counted-vmcnt 2-deep, swizzled LDS ----------------
// KSPLIT>1: blockIdx.y selects K-slice; EPI 4 = atomicAdd f32.
template<int EPI, int KSPLIT = 1>
__global__ __launch_bounds__(256) void k_gemm_bt(
    const __hip_bfloat16* __restrict__ A, const __hip_bfloat16* __restrict__ BT,
    void* __restrict__ Cv, int M, int N, int K) {
  __shared__ __hip_bfloat16 As[2][128][64];   // 32 KiB
  __shared__ __hip_bfloat16 Bs[2][128][64];   // 32 KiB
  int nm = M >> 7;
  int bid = blockIdx.x;
  int mt, nt;
  if (nm == 16) {
    int xcd = bid & 7;
    int seq = bid >> 3;
    mt = (xcd << 1) | (seq & 1);
    nt = seq >> 1;
  } else {
    mt = bid % nm;
    nt = bid / nm;
  }
  int bm = mt << 7, bn = nt << 7;
  const int Keff = K / KSPLIT;
  const int kbase = (KSPLIT > 1) ? (int)blockIdx.y * Keff : 0;
  int tid  = threadIdx.x;
  int wave = tid >> 6, lane = tid & 63;
  int wr = (wave >> 1) * 64, wc = (wave & 1) * 64;
  int g = lane >> 4, c = lane & 15;
  f32x4 acc[4][4] = {};

  auto stage = [&](int buf, int k0) {   // 8 vmem insts/wave
#pragma unroll
    for (int i = 0; i < 4; ++i) {
      int ci = i * 256 + tid;            // 0..1023
      int row = ci >> 3, pc = ci & 7;
      int jl = pc ^ (row & 7);
      gload_lds16(A + (size_t)(bm + row) * K + kbase + k0 + jl * 8, &As[buf][row][pc * 8]);
      gload_lds16(BT + (size_t)(bn + row) * K + kbase + k0 + jl * 8, &Bs[buf][row][pc * 8]);
    }
  };

  int ntiles = Keff >> 6;
  stage(0, 0);
  if (ntiles > 1) stage(1, 64);

  for (int t = 0; t < ntiles; ++t) {
    int cur = t & 1;
    if (t + 1 < ntiles) asm volatile("s_waitcnt vmcnt(8)" ::: "memory");
    else                asm volatile("s_waitcnt vmcnt(0)" ::: "memory");
    __builtin_amdgcn_s_barrier();
    FENCE();
    __builtin_amdgcn_sched_barrier(0);
#pragma unroll
    for (int kk = 0; kk < 2; ++kk) {
      bf16x8 af[4], bv[4];
#pragma unroll
      for (int mi = 0; mi < 4; ++mi) {
        int row = wr + mi * 16 + c;
        int ch = (kk * 4 + g) ^ (row & 7);
        af[mi] = *(const bf16x8*)&As[cur][row][ch * 8];
      }
#pragma unroll
      for (int ni = 0; ni < 4; ++ni) {
        int row = wc + ni * 16 + c;
        int ch = (kk * 4 + g) ^ (row & 7);
        bv[ni] = *(const bf16x8*)&Bs[cur][row][ch * 8];
      }
      __builtin_amdgcn_s_setprio(1);
#pragma unroll
      for (int mi = 0; mi < 4; ++mi)
#pragma unroll
        for (int ni = 0; ni < 4; ++ni)
          acc[mi][ni] = __builtin_amdgcn_mfma_f32_16x16x32_bf16(af[mi], bv[ni], acc[mi][ni], 0, 0, 0);
      __builtin_amdgcn_s_setprio(0);
    }
    FENCE();
    __builtin_amdgcn_s_barrier();
    FENCE();
    if (t + 2 < ntiles) stage(cur, (t + 2) << 6);
  }

  float* Cf = (float*)Cv;
  __hip_bfloat16* Cb = (__hip_bfloat16*)Cv;
#pragma unroll
  for (int mi = 0; mi < 4; ++mi)
#pragma unroll
    for (int ni = 0; ni < 4; ++ni)
#pragma unroll
      for (int r = 0; r < 4; ++r) {
        int row = bm + wr + mi * 16 + g * 4 + r;
        int col = bn + wc + ni * 16 + c;
        size_t idx = (size_t)row * N + col;
        if (EPI == 0) Cf[idx] = acc[mi][ni][r];
        else if (EPI == 1) Cf[idx] += acc[mi][ni][r];
        else if (EPI == 2) Cb[idx] = __float2bfloat16(acc[mi][ni][r]);
        else atomicAdd(&Cf[idx], acc[mi][ni][r]);
      }
}

// ---------------- fallback GEMM: B from f32 weights ----------------
template<int EPI>
__global__ __launch_bounds__(256) void k_gemm(
    const __hip_bfloat16* __restrict__ A, const float* __restrict__ Bw,
    void* __restrict__ Cv, int M, int N, int K) {
  __shared__ __hip_bfloat16 As[128][32];
  __shared__ __hip_bfloat16 Bs[128][40];
  int tid  = threadIdx.x;
  int bm = blockIdx.y * 128, bn = blockIdx.x * 128;
  int wave = tid >> 6, lane = tid & 63;
  int wr = (wave >> 1) * 64, wc = (wave & 1) * 64;
  int lrow = lane & 15, lk = (lane >> 4) * 8;
  f32x4 acc[4][4] = {};
  for (int k0 = 0; k0 < K; k0 += 32) {
#pragma unroll
    for (int i = 0; i < 2; ++i) {
      int L = i * 256 + tid;
      int row = L >> 2, koff = (L & 3) * 8;
      gload_lds16(A + (size_t)(bm + row) * K + k0 + koff, &As[row][koff]);
    }
#pragma unroll
    for (int i = 0; i < 4; ++i) {
      int L = i * 256 + tid;
      int kk = L >> 5;
      int c4 = (L & 31) * 4;
      f32x4 v = *(const f32x4*)(Bw + (size_t)(k0 + kk) * N + bn + c4);
#pragma unroll
      for (int j = 0; j < 4; ++j) Bs[c4 + j][kk] = __float2bfloat16(v[j]);
    }
    __syncthreads();
    bf16x8 af[4], bfr[4];
#pragma unroll
    for (int mi = 0; mi < 4; ++mi)
      af[mi] = *(const bf16x8*)(&As[wr + mi * 16 + lrow][lk]);
#pragma unroll
    for (int ni = 0; ni < 4; ++ni)
      bfr[ni] = *(const bf16x8*)(&Bs[wc + ni * 16 + lrow][lk]);
#pragma unroll
    for (int mi = 0; mi < 4; ++mi)
#pragma unroll
      for (int ni = 0; ni < 4; ++ni)
        acc[mi][ni] = __builtin_amdgcn_mfma_f32_16x16x32_bf16(af[mi], bfr[ni], acc[mi][ni], 0, 0, 0);
    __syncthreads();
  }
  float* Cf = (float*)Cv;
  __hip_bfloat16* Cb = (__hip_bfloat16*)Cv;
#pragma unroll
  for (int mi = 0; mi < 4; ++mi)
#pragma unroll
    for (int ni = 0; ni < 4; ++ni)
#pragma unroll
      for (int r = 0; r < 4; ++r) {
        int row = bm + wr + mi * 16 + ((lane >> 4) * 4 + r);
        int col = bn + wc + ni * 16 + (lane & 15);
        size_t idx = (size_t)row * N + col;
        if (EPI == 0) Cf[idx] = acc[mi][ni][r];
        else if (EPI == 1) Cf[idx] += acc[mi][ni][r];
        else Cb[idx] = __float2bfloat16(acc[mi][ni][r]);
      }
}

// ---------------- RoPE + QKV split/reorder (bf16 input; Q pre-scaled, V transposed) ----------------
__global__ __launch_bounds__(256) void k_rope(const __hip_bfloat16* __restrict__ qkv,
    __hip_bfloat16* __restrict__ qr, __hip_bfloat16* __restrict__ kr,
    __hip_bfloat16* __restrict__ vt) {
  int rowid = blockIdx.x;
  int b = rowid >> 10, s = rowid & (S_LEN - 1);
  const __hip_bfloat16* src = qkv + (size_t)rowid * 3072;
  const float kInvLog = 0.20503692777f;  // ln(500000)/64
  const float scale = 0.08838834764831845f;  // 1/sqrt(128)
  __shared__ float cs[64], sn[64];
  if (threadIdx.x < 64) {
    float inv = expf(-(float)threadIdx.x * kInvLog);
    float a = (float)s * inv;
    sincosf(a, &sn[threadIdx.x], &cs[threadIdx.x]);
  }
  __syncthreads();
  for (int it = threadIdx.x; it < NHQ * 64; it += 256) {
    int h = it >> 6, i = it & 63;
    float re = __bfloat162float(src[h * HDIM + i]);
    float im = __bfloat162float(src[h * HDIM + 64 + i]);
    size_t dst = ((size_t)(b * NHQ + h) * S_LEN + s) * HDIM;
    qr[dst + 2 * i]     = __float2bfloat16((re * cs[i] - im * sn[i]) * scale);
    qr[dst + 2 * i + 1] = __float2bfloat16((re * sn[i] + im * cs[i]) * scale);
  }
  for (int it = threadIdx.x; it < NHKV * 64; it += 256) {
    int h = it >> 6, i = it & 63;
    float re = __bfloat162float(src[DIM + h * HDIM + i]);
    float im = __bfloat162float(src[DIM + h * HDIM + 64 + i]);
    size_t dst = ((size_t)(b * NHKV + h) * S_LEN + s) * HDIM;
    kr[dst + 2 * i]     = __float2bfloat16(re * cs[i] - im * sn[i]);
    kr[dst + 2 * i + 1] = __float2bfloat16(re * sn[i] + im * cs[i]);
  }
  // V transposed: vt[b][hk][hd][s]
  for (int it = threadIdx.x; it < NHKV * HDIM; it += 256) {
    int h = it >> 7, d = it & 127;
    vt[(((size_t)b * NHKV + h) * HDIM + d) * S_LEN + s] = src[DIM + NHKV * HDIM + it];
  }
}

// ---------------- MFMA flash attention: 32 q-rows/wave, shared K/V tiles ----------------
__global__ __launch_bounds__(256) void k_attn_mfma(
    const __hip_bfloat16* __restrict__ Q,   // [B][HQ][S][HD]
    const __hip_bfloat16* __restrict__ Kc,  // [B][HKV][S][HD]
    const __hip_bfloat16* __restrict__ VT,  // [B][HKV][HD][S]
    __hip_bfloat16* __restrict__ O) {       // [B*S][2048], col = h*128+d
  __shared__ __hip_bfloat16 plds[4][32][40];
  int wave = threadIdx.x >> 6, lane = threadIdx.x & 63;
  int gw = blockIdx.x * 4 + wave;     // 0 .. B*HQ*(S/32)-1
  int qt = gw & 31;
  int bh = gw >> 5;                   // b*HQ + h
  int b = bh >> 4, h = bh & 15;
  int hk = h >> 2;
  int q0 = qt * 32;
  int g = lane >> 4, c = lane & 15;
  const __hip_bfloat16* Qb = Q + ((size_t)bh * S_LEN + q0) * HDIM;
  const __hip_bfloat16* Kb = Kc + (size_t)(b * NHKV + hk) * S_LEN * HDIM;
  const __hip_bfloat16* Vb = VT + (size_t)(b * NHKV + hk) * S_LEN * HDIM;

  bf16x8 qf[2][4];
#pragma unroll
  for (int f = 0; f < 2; ++f)
#pragma unroll
    for (int cn = 0; cn < 4; ++cn)
      qf[f][cn] = *(const bf16x8*)(Qb + (size_t)(f * 16 + c) * HDIM + cn * 32 + g * 8);

  f32x4 po[2][8] = {};
  float m[2][4], l[2][4];
#pragma unroll
  for (int f = 0; f < 2; ++f)
#pragma unroll
    for (int r = 0; r < 4; ++r) { m[f][r] = -1e30f; l[f][r] = 0.f; }

  int kvend = q0 + 32;
  for (int kv0 = 0; kv0 < kvend; kv0 += 32) {
    f32x4 s0[2] = {}, s1[2] = {};
#pragma unroll
    for (int cn = 0; cn < 4; ++cn) {
      bf16x8 k0f = *(const bf16x8*)(Kb + (size_t)(kv0 + c) * HDIM + cn * 32 + g * 8);
      bf16x8 k1f = *(const bf16x8*)(Kb + (size_t)(kv0 + 16 + c) * HDIM + cn * 32 + g * 8);
#pragma unroll
      for (int f = 0; f < 2; ++f) {
        s0[f] = __builtin_amdgcn_mfma_f32_16x16x32_bf16(qf[f][cn], k0f, s0[f], 0, 0, 0);
        s1[f] = __builtin_amdgcn_mfma_f32_16x16x32_bf16(qf[f][cn], k1f, s1[f], 0, 0, 0);
      }
    }
    if (kv0 + 31 > q0) {               // aligned diagonal tile only (kv0 == q0)
#pragma unroll
      for (int f = 0; f < 2; ++f)
#pragma unroll
        for (int r = 0; r < 4; ++r) {
          int qrow = q0 + f * 16 + g * 4 + r;
          if (kv0 + c > qrow)      s0[f][r] = -1e30f;
          if (kv0 + 16 + c > qrow) s1[f][r] = -1e30f;
        }
    }
#pragma unroll
    for (int f = 0; f < 2; ++f) {
      float rm[4];
#pragma unroll
      for (int r = 0; r < 4; ++r) rm[r] = fmaxf(s0[f][r], s1[f][r]);
#pragma unroll
      for (int off = 1; off < 16; off <<= 1)
#pragma unroll
        for (int r = 0; r < 4; ++r) rm[r] = fmaxf(rm[r], __shfl_xor(rm[r], off));
      float p0[4], p1[4], rs[4];
#pragma unroll
      for (int r = 0; r < 4; ++r) {
        float mn = fmaxf(m[f][r], rm[r]);
        float corr = __expf(m[f][r] - mn);
        m[f][r] = mn;
        p0[r] = __expf(s0[f][r] - mn);
        p1[r] = __expf(s1[f][r] - mn);
        rs[r] = p0[r] + p1[r];
        l[f][r] *= corr;
#pragma unroll
        for (int t = 0; t < 8; ++t) po[f][t][r] *= corr;
      }
#pragma unroll
      for (int off = 1; off < 16; off <<= 1)
#pragma unroll
        for (int r = 0; r < 4; ++r) rs[r] += __shfl_xor(rs[r], off);
#pragma unroll
      for (int r = 0; r < 4; ++r) l[f][r] += rs[r];
#pragma unroll
      for (int r = 0; r < 4; ++r) {
        plds[wave][f * 16 + g * 4 + r][c]      = __float2bfloat16(p0[r]);
        plds[wave][f * 16 + g * 4 + r][16 + c] = __float2bfloat16(p1[r]);
      }
    }
    bf16x8 pf[2];
#pragma unroll
    for (int f = 0; f < 2; ++f)
      pf[f] = *(const bf16x8*)&plds[wave][f * 16 + c][g * 8];
#pragma unroll
    for (int t = 0; t < 8; ++t) {
      bf16x8 vf = *(const bf16x8*)(Vb + (size_t)(t * 16 + c) * S_LEN + kv0 + g * 8);
#pragma unroll
      for (int f = 0; f < 2; ++f)
        po[f][t] = __builtin_amdgcn_mfma_f32_16x16x32_bf16(pf[f], vf, po[f][t], 0, 0, 0);
    }
  }
#pragma unroll
  for (int f = 0; f < 2; ++f) {
    float inv[4];
#pragma unroll
    for (int r = 0; r < 4; ++r) inv[r] = 1.f / l[f][r];
    __hip_bfloat16* ob = O + ((size_t)(b * S_LEN) + q0 + f * 16) * DIM + h * HDIM;
#pragma unroll
    for (int t = 0; t < 8; ++t)
#pragma unroll
      for (int r = 0; r < 4; ++r)
        ob[(size_t)(g * 4 + r) * DIM + t * 16 + c] = __float2bfloat16(po[f][t][r] * inv[r]);
  }
}

extern "C" void kernel_launch(void* const* d_in, const int* in_sizes, int n_in,
                              void* d_out, int out_size, void* d_ws, size_t ws_size,
                              hipStream_t stream) {
  const int*   tokens    = (const int*)d_in[0];
  const float* emb       = (const float*)d_in[1];
  const float* w_qkv     = (const float*)d_in[2];
  const float* w_o       = (const float*)d_in[3];
  const float* w_gate_up = (const float*)d_in[4];
  const float* w_down    = (const float*)d_in[5];
  const float* ln_attn   = (const float*)d_in[6];
  const float* ln_ffn    = (const float*)d_in[7];
  const float* ln_f      = (const float*)d_in[8];
  const float* w_lm      = (const float*)d_in[9];
  float* out = (float*)d_out;

  char* ws = (char*)d_ws;
  float* x = (float*)ws;                    ws += (size_t)NROWS * DIM * 4;
  __hip_bfloat16* xn = (__hip_bfloat16*)ws; ws += (size_t)NROWS * DIM * 2;
  __hip_bfloat16* qkvb = (__hip_bfloat16*)ws; ws += (size_t)NROWS * 3072 * 2;
  __hip_bfloat16* qr = (__hip_bfloat16*)ws; ws += (size_t)2 * NHQ * S_LEN * HDIM * 2;
  __hip_bfloat16* kr = (__hip_bfloat16*)ws; ws += (size_t)2 * NHKV * S_LEN * HDIM * 2;
  __hip_bfloat16* vt = (__hip_bfloat16*)ws; ws += (size_t)2 * NHKV * S_LEN * HDIM * 2;
  __hip_bfloat16* ao = (__hip_bfloat16*)ws; ws += (size_t)NROWS * DIM * 2;
  __hip_bfloat16* hb = (__hip_bfloat16*)ws; ws += (size_t)NROWS * PDIM * 2;
  __hip_bfloat16* wbuf = (__hip_bfloat16*)ws;           // JIT bf16 W^T buffer
  size_t need = (size_t)(ws - (char*)d_ws) + (size_t)VOCAB * DIM * 2;
  bool bf16w = ws_size >= need;

  k_embed<<<NROWS, 256, 0, stream>>>(tokens, emb, x);

  for (int l = 0; l < NLAYER; ++l) {
    k_rmsnorm<<<NROWS, 512, 0, stream>>>(x, ln_attn + (size_t)l * DIM, xn);
    if (bf16w) {
      k_wt<<<dim3(3072 / 64, DIM / 64), 256, 0, stream>>>(
          w_qkv + (size_t)l * DIM * 3072, wbuf, DIM, 3072);
      k_gemm_bt<2><<<(NROWS / 128) * (3072 / 128), 256, 0, stream>>>(
          xn, wbuf, qkvb, NROWS, 3072, DIM);
    } else {
      k_gemm<2><<<dim3(3072 / 128, NROWS / 128), 256, 0, stream>>>(
          xn, w_qkv + (size_t)l * DIM * 3072, qkvb, NROWS, 3072, DIM);
    }
    k_rope<<<NROWS, 256, 0, stream>>>(qkvb, qr, kr, vt);
    k_attn_mfma<<<(2 * NHQ * (S_LEN / 32)) / 4, 256, 0, stream>>>(qr, kr, vt, ao);
    if (bf16w) {
      k_wt<<<dim3(DIM / 64, DIM / 64), 256, 0, stream>>>(
          w_o + (size_t)l * DIM * DIM, wbuf, DIM, DIM);
      k_gemm_bt<4, 2><<<dim3((NROWS / 128) * (DIM / 128), 2), 256, 0, stream>>>(
          ao, wbuf, x, NROWS, DIM, DIM);
    } else {
      k_gemm<1><<<dim3(DIM / 128, NROWS / 128), 256, 0, stream>>>(
          ao, w_o + (size_t)l * DIM * DIM, x, NROWS, DIM, DIM);
    }
    k_rmsnorm<<<NROWS, 512, 0, stream>>>(x, ln_ffn + (size_t)l * DIM, xn);
    if (bf16w) {
      k_wt_gu<<<dim3(2 * PDIM / 64, DIM / 64), 256, 0, stream>>>(
          w_gate_up + (size_t)l * DIM * 2 * PDIM, wbuf, DIM, 2 * PDIM);
      k_gemm256<3><<<8 * (2 * PDIM / 256), 512, 0, stream>>>(
          xn, wbuf, hb, NROWS, 2 * PDIM, DIM);
    } else {
      k_gemm<2><<<dim3(2 * PDIM / 128, NROWS / 128), 256, 0, stream>>>(
          xn, w_gate_up + (size_t)l * DIM * 2 * PDIM, (void*)hb, NROWS, 2 * PDIM, DIM);
    }
    if (bf16w) {
      k_wt<<<dim3(DIM / 64, PDIM / 64), 256, 0, stream>>>(
          w_down + (size_t)l * PDIM * DIM, wbuf, PDIM, DIM);
      k_gemm_bt<4, 2><<<dim3((NROWS / 128) * (DIM / 128), 2), 256, 0, stream>>>(
          hb, wbuf, x, NROWS, DIM, PDIM);
    } else {
      k_gemm<1><<<dim3(DIM / 128, NROWS / 128), 256, 0, stream>>>(
          hb, w_down + (size_t)l * PDIM * DIM, x, NROWS, DIM, PDIM);
    }
  }

  k_rmsnorm<<<NROWS, 512, 0, stream>>>(x, ln_f, xn);
  if (bf16w) {
    k_wt<<<dim3(VOCAB / 64, DIM / 64), 256, 0, stream>>>(w_lm, wbuf, DIM, VOCAB);
    k_gemm256<0><<<8 * (VOCAB / 256), 512, 0, stream>>>(
        xn, wbuf, out, NROWS, VOCAB, DIM);
  } else {
    k_gemm<0><<<dim3(VOCAB / 128, NROWS / 128), 256, 0, stream>>>(
        xn, w_lm, out, NROWS, VOCAB, DIM);
  }
}